// Round 3
// baseline (298.077 us; speedup 1.0000x reference)
//
#include <hip/hip_runtime.h>
#include <hip/hip_fp16.h>

#define NPTS 100000
#define NB 500
#define KNN 100
#define KPN 15
#define C1 128
#define C2 1024
#define C3 512
#define C4 256

// ---- L-inf kNN grid parameters
#define G 64
#define NCELLS (G * G * G)
#define GB 5.0f
#define GINVH ((float)G / (2.f * GB))  // 6.4 cells per unit
#define CAND_CAP 2048

typedef _Float16 half8 __attribute__((ext_vector_type(8)));
typedef float f32x4 __attribute__((ext_vector_type(4)));

// ------------------------------------------------- prep: gather + converts
__global__ __launch_bounds__(256) void prep_kernel(
    const float* __restrict__ pts, const float* __restrict__ normal,
    const int* __restrict__ index, const float* __restrict__ w1,
    const float* __restrict__ kpw, float* __restrict__ sel,
    float* __restrict__ out2, __half* __restrict__ wh,
    __half* __restrict__ kpwT_hi, __half* __restrict__ kpwT_lo) {
  int i = blockIdx.x * 256 + threadIdx.x;
  if (i < NB) {
    int ix = index[i];
    sel[i * 3 + 0] = pts[3 * ix + 0];
    sel[i * 3 + 1] = pts[3 * ix + 1];
    sel[i * 3 + 2] = pts[3 * ix + 2];
    out2[i * 3 + 0] = normal[3 * ix + 0];
    out2[i * 3 + 1] = normal[3 * ix + 1];
    out2[i * 3 + 2] = normal[3 * ix + 2];
  }
  if (i < C2 * C1) wh[i] = __float2half(w1[i]);
  if (i < 128 * 64) {
    int o = i >> 6, j = i & 63;
    float v = (j < 45) ? kpw[j * 128 + o] : 0.f;
    __half hi = __float2half_rn(v);
    kpwT_hi[i] = hi;
    kpwT_lo[i] = __float2half_rn(v - __half2float(hi));
  }
}

// ------------------------------------------------- grid build (counting sort)
__device__ __forceinline__ int cell_coord(float x) {
  int c = (int)floorf((x + GB) * GINVH);
  return min(max(c, 0), G - 1);
}
__device__ __forceinline__ int cell_of(float x, float y, float z) {
  return (cell_coord(x) << 12) | (cell_coord(y) << 6) | cell_coord(z);
}

__global__ __launch_bounds__(256) void grid_hist_kernel(
    const float* __restrict__ pts, unsigned* __restrict__ cnt) {
  int i = blockIdx.x * 256 + threadIdx.x;
  if (i >= NPTS) return;
  atomicAdd(&cnt[cell_of(pts[3 * i], pts[3 * i + 1], pts[3 * i + 2])], 1u);
}

__global__ __launch_bounds__(256) void grid_scan1_kernel(
    const unsigned* __restrict__ cnt, unsigned* __restrict__ cursor,
    unsigned* __restrict__ chunktot) {
  const int tid = threadIdx.x;
  int base = blockIdx.x * 1024 + tid * 4;
  unsigned c0 = cnt[base], c1 = cnt[base + 1], c2 = cnt[base + 2],
           c3 = cnt[base + 3];
  unsigned tot = c0 + c1 + c2 + c3;
  __shared__ unsigned sb[256];
  sb[tid] = tot;
  __syncthreads();
  for (int off = 1; off < 256; off <<= 1) {
    unsigned add = (tid >= off) ? sb[tid - off] : 0u;
    __syncthreads();
    sb[tid] += add;
    __syncthreads();
  }
  unsigned excl = sb[tid] - tot;
  cursor[base] = excl;
  cursor[base + 1] = excl + c0;
  cursor[base + 2] = excl + c0 + c1;
  cursor[base + 3] = excl + c0 + c1 + c2;
  if (tid == 255) chunktot[blockIdx.x] = sb[255];
}

__global__ __launch_bounds__(256) void grid_scan2_kernel(
    const unsigned* __restrict__ chunktot, unsigned* __restrict__ chunkoff) {
  const int tid = threadIdx.x;
  unsigned v = chunktot[tid];
  __shared__ unsigned sb[256];
  sb[tid] = v;
  __syncthreads();
  for (int off = 1; off < 256; off <<= 1) {
    unsigned add = (tid >= off) ? sb[tid - off] : 0u;
    __syncthreads();
    sb[tid] += add;
    __syncthreads();
  }
  chunkoff[tid] = sb[tid] - v;
}

__global__ __launch_bounds__(256) void grid_scan3_kernel(
    unsigned* __restrict__ cursor, const unsigned* __restrict__ chunkoff) {
  unsigned off = chunkoff[blockIdx.x];
  int base = blockIdx.x * 1024 + threadIdx.x * 4;
#pragma unroll
  for (int j = 0; j < 4; ++j) cursor[base + j] += off;
}

// scatter: cursor turns into per-cell END offsets; begin = end - cnt
__global__ __launch_bounds__(256) void grid_scatter_kernel(
    const float* __restrict__ pts, unsigned* __restrict__ cursor,
    float4* __restrict__ sorted) {
  int i = blockIdx.x * 256 + threadIdx.x;
  if (i >= NPTS) return;
  float x = pts[3 * i], y = pts[3 * i + 1], z = pts[3 * i + 2];
  unsigned pos = atomicAdd(&cursor[cell_of(x, y, z)], 1u);
  sorted[pos] = make_float4(x, y, z, __int_as_float(i));
}

// ---------------------------------------------------------------- kNN v5
// Grid-accelerated exact L-inf kNN. Per query: expand cell-cube to >=100
// points; collect + histogram-select an upper bound on the 100th distance;
// re-collect the exact cover cube filtered by that bound; exact rank-select
// with index tie-break (matches stable top_k; downstream is order-invariant).
__device__ __forceinline__ unsigned linf_bits(float px, float py, float pz,
                                              float sx, float sy, float sz) {
  float dx = fabsf(px - sx), dy = fabsf(py - sy), dz = fabsf(pz - sz);
  return __float_as_uint(fmaxf(fmaxf(dx, dy), dz));
}

__global__ __launch_bounds__(256) void knn_kernel(
    const float4* __restrict__ sorted, const unsigned* __restrict__ cnt,
    const unsigned* __restrict__ cursor,  // per-cell end offsets
    const float* __restrict__ sel, int* __restrict__ nbr) {
  const int b = blockIdx.x;
  const int tid = threadIdx.x;
  __shared__ unsigned cbits[CAND_CAP];
  __shared__ int cidx[CAND_CAP];
  __shared__ unsigned hist[4096];
  __shared__ unsigned scanbuf[256];
  __shared__ int s_total, s_m, s_mc, s_chunk;
  __shared__ unsigned s_excl, s_bub;

  const float qx = sel[b * 3 + 0], qy = sel[b * 3 + 1], qz = sel[b * 3 + 2];
  const int qcx = cell_coord(qx), qcy = cell_coord(qy), qcz = cell_coord(qz);

  // ---------------- Phase A: expand cube until >=KNN points counted
  int s = 0;
  int xlo, xhi, ylo, yhi, zlo, zhi;
  for (;;) {
    if (tid == 0) s_total = 0;
    __syncthreads();
    xlo = max(qcx - s, 0); xhi = min(qcx + s, G - 1);
    ylo = max(qcy - s, 0); yhi = min(qcy + s, G - 1);
    zlo = max(qcz - s, 0); zhi = min(qcz + s, G - 1);
    int nx = xhi - xlo + 1, ny = yhi - ylo + 1, nz = zhi - zlo + 1;
    int ncell = nx * ny * nz;
    unsigned local = 0;
    for (int ci = tid; ci < ncell; ci += 256) {
      int cz = ci % nz;
      int r = ci / nz;
      int cy = r % ny;
      int cx = r / ny;
      local += cnt[((xlo + cx) << 12) | ((ylo + cy) << 6) | (zlo + cz)];
    }
#pragma unroll
    for (int off = 32; off; off >>= 1) local += __shfl_down(local, off);
    if ((tid & 63) == 0) atomicAdd(&s_total, (int)local);
    __syncthreads();
    if (s_total >= KNN || (xlo == 0 && ylo == 0 && zlo == 0 && xhi == G - 1 &&
                           yhi == G - 1 && zhi == G - 1))
      break;
    ++s;
    __syncthreads();
  }

  // ---------------- Phase B: collect cube points (capped; >=KNN kept)
  if (tid == 0) s_m = 0;
  __syncthreads();
  {
    int nx = xhi - xlo + 1, ny = yhi - ylo + 1, nz = zhi - zlo + 1;
    int ncell = nx * ny * nz;
    for (int ci = tid; ci < ncell; ci += 256) {
      int cz = ci % nz;
      int r = ci / nz;
      int cy = r % ny;
      int cx = r / ny;
      int cell = ((xlo + cx) << 12) | ((ylo + cy) << 6) | (zlo + cz);
      unsigned end = cursor[cell];
      unsigned beg = end - cnt[cell];
      for (unsigned p = beg; p < end; ++p) {
        float4 f = sorted[p];
        unsigned bits = linf_bits(f.x, f.y, f.z, qx, qy, qz);
        int e = atomicAdd(&s_m, 1);
        if (e < CAND_CAP) {
          cbits[e] = bits;
          cidx[e] = __float_as_int(f.w);
        }
      }
    }
  }
  __syncthreads();
  int m = s_m < CAND_CAP ? s_m : CAND_CAP;

  // ---------------- histogram select: upper bound on 100th distance
  for (int j = tid; j < 4096; j += 256) hist[j] = 0;
  __syncthreads();
  for (int e = tid; e < m; e += 256) atomicAdd(&hist[cbits[e] >> 19], 1u);
  __syncthreads();
  unsigned csum = 0;
  {
    int c0 = tid * 16;
#pragma unroll
    for (int j = 0; j < 16; ++j) csum += hist[c0 + j];
  }
  scanbuf[tid] = csum;
  __syncthreads();
  for (int off = 1; off < 256; off <<= 1) {
    unsigned add = (tid >= off) ? scanbuf[tid - off] : 0u;
    __syncthreads();
    scanbuf[tid] += add;
    __syncthreads();
  }
  {
    unsigned incl = scanbuf[tid], excl = incl - csum;
    if (excl < KNN && KNN <= incl) {
      s_chunk = tid;
      s_excl = excl;
    }
  }
  __syncthreads();
  if (tid == 0) {
    unsigned cum = s_excl;
    int bin = s_chunk * 16;
    while (cum + hist[bin] < KNN) {
      cum += hist[bin];
      ++bin;
    }
    s_bub = (unsigned)(bin + 1) << 19;  // exclusive upper bound on bits
  }
  __syncthreads();

  // ---------------- Phase C: exact cover cube, filter bits < bound
  const unsigned bub = s_bub;
  const float dub = __uint_as_float(bub);
  if (tid == 0) s_mc = 0;
  __syncthreads();
  {
    int xlo2 = min(max((int)floorf((qx - dub + GB) * GINVH), 0), G - 1);
    int xhi2 = min(max((int)floorf((qx + dub + GB) * GINVH), 0), G - 1);
    int ylo2 = min(max((int)floorf((qy - dub + GB) * GINVH), 0), G - 1);
    int yhi2 = min(max((int)floorf((qy + dub + GB) * GINVH), 0), G - 1);
    int zlo2 = min(max((int)floorf((qz - dub + GB) * GINVH), 0), G - 1);
    int zhi2 = min(max((int)floorf((qz + dub + GB) * GINVH), 0), G - 1);
    int nx = xhi2 - xlo2 + 1, ny = yhi2 - ylo2 + 1, nz = zhi2 - zlo2 + 1;
    int ncell = nx * ny * nz;
    for (int ci = tid; ci < ncell; ci += 256) {
      int cz = ci % nz;
      int r = ci / nz;
      int cy = r % ny;
      int cx = r / ny;
      int cell = ((xlo2 + cx) << 12) | ((ylo2 + cy) << 6) | (zlo2 + cz);
      unsigned end = cursor[cell];
      unsigned beg = end - cnt[cell];
      for (unsigned p = beg; p < end; ++p) {
        float4 f = sorted[p];
        unsigned bits = linf_bits(f.x, f.y, f.z, qx, qy, qz);
        if (bits < bub) {
          int e = atomicAdd(&s_mc, 1);
          if (e < CAND_CAP) {
            cbits[e] = bits;
            cidx[e] = __float_as_int(f.w);
          }
        }
      }
    }
  }
  __syncthreads();
  int mc = s_mc < CAND_CAP ? s_mc : CAND_CAP;

  // ---------------- exact rank-select (ties by original index, stable)
  for (int c = tid; c < mc; c += 256) {
    unsigned bc = cbits[c];
    int ic = cidx[c];
    int rank = 0;
    for (int j = 0; j < mc; ++j) {
      unsigned bj = cbits[j];
      rank += (bj < bc || (bj == bc && cidx[j] < ic)) ? 1 : 0;
    }
    if (rank < KNN) nbr[b * KNN + rank] = ic;
  }
}

// ------------------------------------------------- KPConv (f16 MFMA, hi/lo)
__global__ __launch_bounds__(256) void kpconv_mfma_kernel(
    const float* __restrict__ pts, const float* __restrict__ sel,
    const int* __restrict__ nbr, const float* __restrict__ kp_points,
    const __half* __restrict__ kpwT_hi, const __half* __restrict__ kpwT_lo,
    const float* __restrict__ kp_sigma, __half* __restrict__ h) {
  const int b = blockIdx.x;
  const int tid = threadIdx.x;
  const int wave = tid >> 6, lane = tid & 63;
  const int lr = lane & 15, quad = lane >> 4;
  __shared__ __half As_hi[112 * 72];  // +8 pad
  __shared__ __half As_lo[112 * 72];
  __shared__ __half Bs_hi[128 * 72];
  __shared__ __half Bs_lo[128 * 72];
  __shared__ float rel[100][4];
  __shared__ float kpp[48];

  for (int i = tid; i < 128 * 8; i += 256) {
    int row = i >> 3, seg = i & 7;
    *(float4*)&Bs_hi[row * 72 + seg * 8] =
        *(const float4*)&kpwT_hi[row * 64 + seg * 8];
    *(float4*)&Bs_lo[row * 72 + seg * 8] =
        *(const float4*)&kpwT_lo[row * 64 + seg * 8];
  }
  {
    float4 z = make_float4(0.f, 0.f, 0.f, 0.f);
    for (int i = tid; i < 112 * 8; i += 256) {
      int row = i >> 3, seg = i & 7;
      *(float4*)&As_hi[row * 72 + seg * 8] = z;
      *(float4*)&As_lo[row * 72 + seg * 8] = z;
    }
  }
  if (tid < 45) kpp[tid] = kp_points[tid];
  if (tid < 100) {
    int idx = nbr[b * KNN + tid];
    rel[tid][0] = pts[3 * idx + 0] - sel[b * 3 + 0];
    rel[tid][1] = pts[3 * idx + 1] - sel[b * 3 + 1];
    rel[tid][2] = pts[3 * idx + 2] - sel[b * 3 + 2];
  }
  __syncthreads();

  const float sg = kp_sigma[0];
  const float inv2s2 = -0.5f / (sg * sg);
  for (int i = tid; i < 100 * KPN; i += 256) {
    int k = i / KPN, p = i - k * KPN;
    float rx = rel[k][0] - kpp[p * 3 + 0];
    float ry = rel[k][1] - kpp[p * 3 + 1];
    float rz = rel[k][2] - kpp[p * 3 + 2];
    float w = expf(inv2s2 * (rx * rx + ry * ry + rz * rz));
#pragma unroll
    for (int c = 0; c < 3; ++c) {
      float a = rel[k][c] * w;
      __half hi = __float2half_rn(a);
      As_hi[k * 72 + p * 3 + c] = hi;
      As_lo[k * 72 + p * 3 + c] = __float2half_rn(a - __half2float(hi));
    }
  }
  __syncthreads();

  f32x4 acc[2][7];
#pragma unroll
  for (int t = 0; t < 2; ++t)
#pragma unroll
    for (int m = 0; m < 7; ++m) acc[t][m] = (f32x4)(0.f);

#pragma unroll
  for (int s = 0; s < 2; ++s) {
    half8 bhi[2], blo[2];
#pragma unroll
    for (int t = 0; t < 2; ++t) {
      int boff = ((wave * 2 + t) * 16 + lr) * 72 + s * 32 + quad * 8;
      bhi[t] = *(const half8*)&Bs_hi[boff];
      blo[t] = *(const half8*)&Bs_lo[boff];
    }
#pragma unroll
    for (int m = 0; m < 7; ++m) {
      int aoff = (m * 16 + lr) * 72 + s * 32 + quad * 8;
      half8 ahi = *(const half8*)&As_hi[aoff];
      half8 alo = *(const half8*)&As_lo[aoff];
#pragma unroll
      for (int t = 0; t < 2; ++t) {
        acc[t][m] = __builtin_amdgcn_mfma_f32_16x16x32_f16(ahi, bhi[t],
                                                           acc[t][m], 0, 0, 0);
        acc[t][m] = __builtin_amdgcn_mfma_f32_16x16x32_f16(ahi, blo[t],
                                                           acc[t][m], 0, 0, 0);
        acc[t][m] = __builtin_amdgcn_mfma_f32_16x16x32_f16(alo, bhi[t],
                                                           acc[t][m], 0, 0, 0);
      }
    }
  }

#pragma unroll
  for (int t = 0; t < 2; ++t) {
    int col = (wave * 2 + t) * 16 + lr;
#pragma unroll
    for (int m = 0; m < 7; ++m)
#pragma unroll
      for (int r = 0; r < 4; ++r) {
        int row = m * 16 + quad * 4 + r;
        if (row < 100)
          h[(b * KNN + row) * 128 + col] =
              __float2half_rn(fmaxf(acc[t][m][r], 0.f));
      }
  }
}

// ------------------------------------------------------- conv1 (f16 MFMA)
__global__ __launch_bounds__(256) void conv1_mfma_kernel(
    const __half* __restrict__ h16, const __half* __restrict__ wh,
    const float* __restrict__ bias, float* __restrict__ featmax,
    float* __restrict__ featmin, float* __restrict__ bnsum,
    float* __restrict__ bnsq) {
  const int b = blockIdx.y;
  const int n0 = blockIdx.x * 128;
  const int tid = threadIdx.x;
  const int wave = tid >> 6, lane = tid & 63;
  const int lr = lane & 15, quad = lane >> 4;
  __shared__ __half Hs[112 * 136];
  __shared__ __half Ws[128 * 136];

  for (int i = tid; i < 112 * 16; i += 256) {
    int row = i >> 4, seg = i & 15;
    float4 v = make_float4(0.f, 0.f, 0.f, 0.f);
    if (row < 100) v = *(const float4*)&h16[(b * 100 + row) * 128 + seg * 8];
    *(float4*)&Hs[row * 136 + seg * 8] = v;
  }
  for (int i = tid; i < 128 * 16; i += 256) {
    int row = i >> 4, seg = i & 15;
    *(float4*)&Ws[row * 136 + seg * 8] =
        *(const float4*)&wh[(n0 + row) * 128 + seg * 8];
  }
  __syncthreads();

  f32x4 acc[2][7];
#pragma unroll
  for (int t = 0; t < 2; ++t)
#pragma unroll
    for (int m = 0; m < 7; ++m) acc[t][m] = (f32x4)(0.f);

#pragma unroll
  for (int s = 0; s < 4; ++s) {
    half8 bfrag[2];
#pragma unroll
    for (int t = 0; t < 2; ++t)
      bfrag[t] =
          *(const half8*)&Ws[((wave * 2 + t) * 16 + lr) * 136 + s * 32 + quad * 8];
#pragma unroll
    for (int m = 0; m < 7; ++m) {
      half8 afrag = *(const half8*)&Hs[(m * 16 + lr) * 136 + s * 32 + quad * 8];
      acc[0][m] =
          __builtin_amdgcn_mfma_f32_16x16x32_f16(afrag, bfrag[0], acc[0][m], 0, 0, 0);
      acc[1][m] =
          __builtin_amdgcn_mfma_f32_16x16x32_f16(afrag, bfrag[1], acc[1][m], 0, 0, 0);
    }
  }

#pragma unroll
  for (int t = 0; t < 2; ++t) {
    int col = n0 + (wave * 2 + t) * 16 + lr;
    float bv = bias[col];
    float pmax = -1e30f, pmin = 1e30f, psum = 0.f, psq = 0.f;
#pragma unroll
    for (int m = 0; m < 7; ++m)
#pragma unroll
      for (int r = 0; r < 4; ++r) {
        int row = m * 16 + quad * 4 + r;
        if (row < 100) {
          float y = fmaxf(acc[t][m][r] + bv, 0.f);
          pmax = fmaxf(pmax, y);
          pmin = fminf(pmin, y);
          psum += y;
          psq += y * y;
        }
      }
    pmax = fmaxf(pmax, __shfl_xor(pmax, 16));
    pmax = fmaxf(pmax, __shfl_xor(pmax, 32));
    pmin = fminf(pmin, __shfl_xor(pmin, 16));
    pmin = fminf(pmin, __shfl_xor(pmin, 32));
    psum += __shfl_xor(psum, 16);
    psum += __shfl_xor(psum, 32);
    psq += __shfl_xor(psq, 16);
    psq += __shfl_xor(psq, 32);
    if (quad == 0) {
      featmax[b * C2 + col] = pmax;
      featmin[b * C2 + col] = pmin;
      atomicAdd(&bnsum[col], psum);
      atomicAdd(&bnsq[col], psq);
    }
  }
}

// ------------------------------------------------------- BN1 + max finalize
__global__ __launch_bounds__(256) void bn1max_kernel(
    const float* __restrict__ featmax, const float* __restrict__ featmin,
    const float* __restrict__ bnsum, const float* __restrict__ bnsq,
    const float* __restrict__ g, const float* __restrict__ bb,
    float* __restrict__ feat1) {
  int idx = blockIdx.x * 256 + threadIdx.x;
  if (idx >= NB * C2) return;
  int o = idx & (C2 - 1);
  const float invn = 1.f / (float)(NB * KNN);
  float m = bnsum[o] * invn;
  float v = bnsq[o] * invn - m * m;
  float a = g[o] / sqrtf(v + 1e-5f);
  float x = (a >= 0.f) ? featmax[idx] : featmin[idx];  // max of monotone map
  feat1[idx] = (x - m) * a + bb[o];
}

// ---------------------------------------------------------------- fc + stats
template <int KDIM>
__global__ __launch_bounds__(256) void fc_relu_stats_kernel(
    const float* __restrict__ x,  // [500][KDIM]
    const float* __restrict__ w,  // [N][KDIM]
    const float* __restrict__ bias, float* __restrict__ yraw,
    float* __restrict__ s, float* __restrict__ sq, int ncols) {
  const int r0 = blockIdx.x * 4;
  const int n0 = blockIdx.y * 64;
  const int tid = threadIdx.x;
  const int col = tid >> 2;  // 0..63
  const int row = tid & 3;
  __shared__ float xs[4][1028];
  __shared__ float ws[64][132];
  for (int f = tid; f < KDIM; f += 256) {  // KDIM float4's total
    int rr = f / (KDIM / 4), kq = (f % (KDIM / 4)) * 4;
    *(float4*)&xs[rr][kq] = *(const float4*)&x[(r0 + rr) * KDIM + kq];
  }
  float acc = 0.f;
  for (int kc = 0; kc < KDIM; kc += 128) {
    __syncthreads();
#pragma unroll
    for (int i = 0; i < 8; ++i) {
      int f = tid + i * 256;  // 0..2047
      int cr = f >> 5, kq = (f & 31) * 4;
      *(float4*)&ws[cr][kq] = *(const float4*)&w[(n0 + cr) * KDIM + kc + kq];
    }
    __syncthreads();
    for (int kk = 0; kk < 128; kk += 4) {
      float4 xv = *(float4*)&xs[row][kc + kk];
      float4 wv = *(float4*)&ws[col][kk];
      acc += xv.x * wv.x + xv.y * wv.y + xv.z * wv.z + xv.w * wv.w;
    }
  }
  float y = fmaxf(acc + bias[n0 + col], 0.f);
  yraw[(r0 + row) * ncols + n0 + col] = y;
  float ys = y, y2 = y * y;
  ys += __shfl_xor(ys, 1); y2 += __shfl_xor(y2, 1);
  ys += __shfl_xor(ys, 2); y2 += __shfl_xor(y2, 2);
  if (row == 0) {
    atomicAdd(&s[n0 + col], ys);
    atomicAdd(&sq[n0 + col], y2);
  }
}

// ---------------------------------------------------------------- BN finalize
__global__ __launch_bounds__(256) void bn_finalize_kernel(
    const float* __restrict__ yraw, const float* __restrict__ s,
    const float* __restrict__ sq, const float* __restrict__ g,
    const float* __restrict__ bb, float* __restrict__ out, int ncols) {
  int idx = blockIdx.x * 256 + threadIdx.x;
  if (idx >= NB * ncols) return;
  int o = idx & (ncols - 1);  // ncols is a power of two
  float m = s[o] * (1.f / (float)NB);
  float v = sq[o] * (1.f / (float)NB) - m * m;
  float a = g[o] / sqrtf(v + 1e-5f);
  out[idx] = (yraw[idx] - m) * a + bb[o];
}

// ---------------------------------------------------------------- fc3
__global__ __launch_bounds__(256) void fc3_kernel(
    const float* __restrict__ feat, const float* __restrict__ w,
    const float* __restrict__ bias, float* __restrict__ out) {
  int idx = blockIdx.x * 256 + threadIdx.x;
  if (idx >= NB * 3) return;
  int b = idx / 3, o = idx % 3;
  float acc = 0.f;
  for (int k = 0; k < C4; ++k) acc += feat[b * C4 + k] * w[o * C4 + k];
  out[idx] = acc + bias[o];
}

// ---------------------------------------------------------------- launch
extern "C" void kernel_launch(void* const* d_in, const int* in_sizes, int n_in,
                              void* d_out, int out_size, void* d_ws,
                              size_t ws_size, hipStream_t stream) {
  const float* pts = (const float*)d_in[0];
  const float* normal = (const float*)d_in[1];
  const float* kp_points = (const float*)d_in[2];
  const float* kp_weights = (const float*)d_in[3];
  const float* kp_sigma = (const float*)d_in[4];
  const float* conv1_w = (const float*)d_in[5];
  const float* conv1_b = (const float*)d_in[6];
  const float* bn1_g = (const float*)d_in[7];
  const float* bn1_b = (const float*)d_in[8];
  const float* fc1_w = (const float*)d_in[9];
  const float* fc1_b = (const float*)d_in[10];
  const float* bn4_g = (const float*)d_in[11];
  const float* bn4_b = (const float*)d_in[12];
  const float* fc2_w = (const float*)d_in[13];
  const float* fc2_b = (const float*)d_in[14];
  const float* bn5_g = (const float*)d_in[15];
  const float* bn5_b = (const float*)d_in[16];
  const float* fc3_w = (const float*)d_in[17];
  const float* fc3_b = (const float*)d_in[18];
  const int* index = (const int*)d_in[19];
  float* out = (float*)d_out;

  char* p = (char*)d_ws;
  auto carve = [&](size_t bytes) {
    void* r = (void*)p;
    p += (bytes + 255) & ~(size_t)255;
    return r;
  };
  float* sel = (float*)carve(NB * 3 * 4);
  int* nbr = (int*)carve(NB * KNN * 4);
  __half* h = (__half*)carve((size_t)NB * KNN * C1 * 2);
  __half* wh = (__half*)carve((size_t)C2 * C1 * 2);
  __half* kpwT_hi = (__half*)carve((size_t)128 * 64 * 2);
  __half* kpwT_lo = (__half*)carve((size_t)128 * 64 * 2);
  float* featmax = (float*)carve(NB * C2 * 4);
  float* featmin = (float*)carve(NB * C2 * 4);
  float* feat1 = (float*)carve(NB * C2 * 4);
  float* f2raw = (float*)carve(NB * C3 * 4);
  float* feat2 = (float*)carve(NB * C3 * 4);
  float* f3raw = (float*)carve(NB * C4 * 4);
  float* feat3 = (float*)carve(NB * C4 * 4);
  float* stats = (float*)carve((2 * C2 + 2 * C3 + 2 * C4) * 4);
  float* bnsum = stats;
  float* bnsq = stats + C2;
  float* s4 = stats + 2 * C2;
  float* sq4 = s4 + C3;
  float* s5 = sq4 + C3;
  float* sq5 = s5 + C4;

  // Grid structures OVERLAY the h buffer (12.8 MB): the grid (3.7 MB) is
  // consumed entirely by knn_kernel, which completes before kpconv writes h.
  // Keeps total workspace footprint identical to the proven round-1 budget.
  {
    char* gp = (char*)h;
    auto gcarve = [&](size_t bytes) {
      void* r = (void*)gp;
      gp += (bytes + 255) & ~(size_t)255;
      return r;
    };
    unsigned* cellcnt = (unsigned*)gcarve((size_t)NCELLS * 4);
    unsigned* cellcur = (unsigned*)gcarve((size_t)NCELLS * 4);
    unsigned* chunktot = (unsigned*)gcarve(256 * 4);
    unsigned* chunkoff = (unsigned*)gcarve(256 * 4);
    float4* sortedpts = (float4*)gcarve((size_t)NPTS * 16);

    hipMemsetAsync(stats, 0, (2 * C2 + 2 * C3 + 2 * C4) * 4, stream);
    hipMemsetAsync(cellcnt, 0, (size_t)NCELLS * 4, stream);

    prep_kernel<<<(C2 * C1 + 255) / 256, 256, 0, stream>>>(
        pts, normal, index, conv1_w, kp_weights, sel, out + NB * 3, wh,
        kpwT_hi, kpwT_lo);
    grid_hist_kernel<<<(NPTS + 255) / 256, 256, 0, stream>>>(pts, cellcnt);
    grid_scan1_kernel<<<256, 256, 0, stream>>>(cellcnt, cellcur, chunktot);
    grid_scan2_kernel<<<1, 256, 0, stream>>>(chunktot, chunkoff);
    grid_scan3_kernel<<<256, 256, 0, stream>>>(cellcur, chunkoff);
    grid_scatter_kernel<<<(NPTS + 255) / 256, 256, 0, stream>>>(pts, cellcur,
                                                                sortedpts);
    knn_kernel<<<NB, 256, 0, stream>>>(sortedpts, cellcnt, cellcur, sel, nbr);
  }

  kpconv_mfma_kernel<<<NB, 256, 0, stream>>>(pts, sel, nbr, kp_points, kpwT_hi,
                                             kpwT_lo, kp_sigma, h);
  conv1_mfma_kernel<<<dim3(8, NB), 256, 0, stream>>>(h, wh, conv1_b, featmax,
                                                     featmin, bnsum, bnsq);
  bn1max_kernel<<<(NB * C2 + 255) / 256, 256, 0, stream>>>(
      featmax, featmin, bnsum, bnsq, bn1_g, bn1_b, feat1);
  fc_relu_stats_kernel<C2><<<dim3(125, C3 / 64), 256, 0, stream>>>(
      feat1, fc1_w, fc1_b, f2raw, s4, sq4, C3);
  bn_finalize_kernel<<<(NB * C3 + 255) / 256, 256, 0, stream>>>(
      f2raw, s4, sq4, bn4_g, bn4_b, feat2, C3);
  fc_relu_stats_kernel<C3><<<dim3(125, C4 / 64), 256, 0, stream>>>(
      feat2, fc2_w, fc2_b, f3raw, s5, sq5, C4);
  bn_finalize_kernel<<<(NB * C4 + 255) / 256, 256, 0, stream>>>(
      f3raw, s5, sq5, bn5_g, bn5_b, feat3, C4);
  fc3_kernel<<<(NB * 3 + 255) / 256, 256, 0, stream>>>(feat3, fc3_w, fc3_b,
                                                       out);
}

// Round 4
// 285.105 us; speedup vs baseline: 1.0455x; 1.0455x over previous
//
#include <hip/hip_runtime.h>
#include <hip/hip_fp16.h>

#define NPTS 100000
#define NB 500
#define KNN 100
#define KPN 15
#define C1 128
#define C2 1024
#define C3 512
#define C4 256

// ---- L-inf kNN grid parameters
#define G 64
#define NCELLS (G * G * G)
#define GB 5.0f
#define GINVH ((float)G / (2.f * GB))  // 6.4 cells per unit
#define CAND_CAP 2048

typedef _Float16 half8 __attribute__((ext_vector_type(8)));
typedef float f32x4 __attribute__((ext_vector_type(4)));

// ------------------------------------------------- prep: gather + converts
__global__ __launch_bounds__(256) void prep_kernel(
    const float* __restrict__ pts, const float* __restrict__ normal,
    const int* __restrict__ index, const float* __restrict__ w1,
    const float* __restrict__ kpw, float* __restrict__ sel,
    float* __restrict__ out2, __half* __restrict__ wh,
    __half* __restrict__ kpwT_hi, __half* __restrict__ kpwT_lo) {
  int i = blockIdx.x * 256 + threadIdx.x;
  if (i < NB) {
    int ix = index[i];
    sel[i * 3 + 0] = pts[3 * ix + 0];
    sel[i * 3 + 1] = pts[3 * ix + 1];
    sel[i * 3 + 2] = pts[3 * ix + 2];
    out2[i * 3 + 0] = normal[3 * ix + 0];
    out2[i * 3 + 1] = normal[3 * ix + 1];
    out2[i * 3 + 2] = normal[3 * ix + 2];
  }
  if (i < C2 * C1) wh[i] = __float2half(w1[i]);
  if (i < 128 * 64) {
    int o = i >> 6, j = i & 63;
    float v = (j < 45) ? kpw[j * 128 + o] : 0.f;
    __half hi = __float2half_rn(v);
    kpwT_hi[i] = hi;
    kpwT_lo[i] = __float2half_rn(v - __half2float(hi));
  }
}

// ------------------------------------------------- grid build (counting sort)
__device__ __forceinline__ int cell_coord(float x) {
  int c = (int)floorf((x + GB) * GINVH);
  return min(max(c, 0), G - 1);
}
__device__ __forceinline__ int cell_of(float x, float y, float z) {
  return (cell_coord(x) << 12) | (cell_coord(y) << 6) | cell_coord(z);
}

__global__ __launch_bounds__(256) void grid_hist_kernel(
    const float* __restrict__ pts, unsigned* __restrict__ cnt) {
  int i = blockIdx.x * 256 + threadIdx.x;
  if (i >= NPTS) return;
  atomicAdd(&cnt[cell_of(pts[3 * i], pts[3 * i + 1], pts[3 * i + 2])], 1u);
}

__global__ __launch_bounds__(256) void grid_scan1_kernel(
    const unsigned* __restrict__ cnt, unsigned* __restrict__ cursor,
    unsigned* __restrict__ chunktot) {
  const int tid = threadIdx.x;
  int base = blockIdx.x * 1024 + tid * 4;
  unsigned c0 = cnt[base], c1 = cnt[base + 1], c2 = cnt[base + 2],
           c3 = cnt[base + 3];
  unsigned tot = c0 + c1 + c2 + c3;
  __shared__ unsigned sb[256];
  sb[tid] = tot;
  __syncthreads();
  for (int off = 1; off < 256; off <<= 1) {
    unsigned add = (tid >= off) ? sb[tid - off] : 0u;
    __syncthreads();
    sb[tid] += add;
    __syncthreads();
  }
  unsigned excl = sb[tid] - tot;
  cursor[base] = excl;
  cursor[base + 1] = excl + c0;
  cursor[base + 2] = excl + c0 + c1;
  cursor[base + 3] = excl + c0 + c1 + c2;
  if (tid == 255) chunktot[blockIdx.x] = sb[255];
}

__global__ __launch_bounds__(256) void grid_scan2_kernel(
    const unsigned* __restrict__ chunktot, unsigned* __restrict__ chunkoff) {
  const int tid = threadIdx.x;
  unsigned v = chunktot[tid];
  __shared__ unsigned sb[256];
  sb[tid] = v;
  __syncthreads();
  for (int off = 1; off < 256; off <<= 1) {
    unsigned add = (tid >= off) ? sb[tid - off] : 0u;
    __syncthreads();
    sb[tid] += add;
    __syncthreads();
  }
  chunkoff[tid] = sb[tid] - v;
}

__global__ __launch_bounds__(256) void grid_scan3_kernel(
    unsigned* __restrict__ cursor, const unsigned* __restrict__ chunkoff) {
  unsigned off = chunkoff[blockIdx.x];
  int base = blockIdx.x * 1024 + threadIdx.x * 4;
#pragma unroll
  for (int j = 0; j < 4; ++j) cursor[base + j] += off;
}

// scatter: cursor turns into per-cell END offsets; begin = end - cnt
__global__ __launch_bounds__(256) void grid_scatter_kernel(
    const float* __restrict__ pts, unsigned* __restrict__ cursor,
    float4* __restrict__ sorted) {
  int i = blockIdx.x * 256 + threadIdx.x;
  if (i >= NPTS) return;
  float x = pts[3 * i], y = pts[3 * i + 1], z = pts[3 * i + 2];
  unsigned pos = atomicAdd(&cursor[cell_of(x, y, z)], 1u);
  sorted[pos] = make_float4(x, y, z, __int_as_float(i));
}

// ---------------------------------------------------------------- kNN v5
__device__ __forceinline__ unsigned linf_bits(float px, float py, float pz,
                                              float sx, float sy, float sz) {
  float dx = fabsf(px - sx), dy = fabsf(py - sy), dz = fabsf(pz - sz);
  return __float_as_uint(fmaxf(fmaxf(dx, dy), dz));
}

__global__ __launch_bounds__(256) void knn_kernel(
    const float4* __restrict__ sorted, const unsigned* __restrict__ cnt,
    const unsigned* __restrict__ cursor,  // per-cell end offsets
    const float* __restrict__ sel, int* __restrict__ nbr) {
  const int b = blockIdx.x;
  const int tid = threadIdx.x;
  __shared__ unsigned cbits[CAND_CAP];
  __shared__ int cidx[CAND_CAP];
  __shared__ unsigned hist[4096];
  __shared__ unsigned scanbuf[256];
  __shared__ int s_total, s_m, s_mc, s_chunk;
  __shared__ unsigned s_excl, s_bub;

  const float qx = sel[b * 3 + 0], qy = sel[b * 3 + 1], qz = sel[b * 3 + 2];
  const int qcx = cell_coord(qx), qcy = cell_coord(qy), qcz = cell_coord(qz);

  // ---------------- Phase A: expand cube until >=KNN points counted
  int s = 0;
  int xlo, xhi, ylo, yhi, zlo, zhi;
  for (;;) {
    if (tid == 0) s_total = 0;
    __syncthreads();
    xlo = max(qcx - s, 0); xhi = min(qcx + s, G - 1);
    ylo = max(qcy - s, 0); yhi = min(qcy + s, G - 1);
    zlo = max(qcz - s, 0); zhi = min(qcz + s, G - 1);
    int nx = xhi - xlo + 1, ny = yhi - ylo + 1, nz = zhi - zlo + 1;
    int ncell = nx * ny * nz;
    unsigned local = 0;
    for (int ci = tid; ci < ncell; ci += 256) {
      int cz = ci % nz;
      int r = ci / nz;
      int cy = r % ny;
      int cx = r / ny;
      local += cnt[((xlo + cx) << 12) | ((ylo + cy) << 6) | (zlo + cz)];
    }
#pragma unroll
    for (int off = 32; off; off >>= 1) local += __shfl_down(local, off);
    if ((tid & 63) == 0) atomicAdd(&s_total, (int)local);
    __syncthreads();
    if (s_total >= KNN || (xlo == 0 && ylo == 0 && zlo == 0 && xhi == G - 1 &&
                           yhi == G - 1 && zhi == G - 1))
      break;
    ++s;
    __syncthreads();
  }

  // ---------------- Phase B: collect cube points (capped; >=KNN kept)
  if (tid == 0) s_m = 0;
  __syncthreads();
  {
    int nx = xhi - xlo + 1, ny = yhi - ylo + 1, nz = zhi - zlo + 1;
    int ncell = nx * ny * nz;
    for (int ci = tid; ci < ncell; ci += 256) {
      int cz = ci % nz;
      int r = ci / nz;
      int cy = r % ny;
      int cx = r / ny;
      int cell = ((xlo + cx) << 12) | ((ylo + cy) << 6) | (zlo + cz);
      unsigned end = cursor[cell];
      unsigned beg = end - cnt[cell];
      for (unsigned p = beg; p < end; ++p) {
        float4 f = sorted[p];
        unsigned bits = linf_bits(f.x, f.y, f.z, qx, qy, qz);
        int e = atomicAdd(&s_m, 1);
        if (e < CAND_CAP) {
          cbits[e] = bits;
          cidx[e] = __float_as_int(f.w);
        }
      }
    }
  }
  __syncthreads();
  int m = s_m < CAND_CAP ? s_m : CAND_CAP;

  // ---------------- histogram select: upper bound on 100th distance
  for (int j = tid; j < 4096; j += 256) hist[j] = 0;
  __syncthreads();
  for (int e = tid; e < m; e += 256) atomicAdd(&hist[cbits[e] >> 19], 1u);
  __syncthreads();
  unsigned csum = 0;
  {
    int c0 = tid * 16;
#pragma unroll
    for (int j = 0; j < 16; ++j) csum += hist[c0 + j];
  }
  scanbuf[tid] = csum;
  __syncthreads();
  for (int off = 1; off < 256; off <<= 1) {
    unsigned add = (tid >= off) ? scanbuf[tid - off] : 0u;
    __syncthreads();
    scanbuf[tid] += add;
    __syncthreads();
  }
  {
    unsigned incl = scanbuf[tid], excl = incl - csum;
    if (excl < KNN && KNN <= incl) {
      s_chunk = tid;
      s_excl = excl;
    }
  }
  __syncthreads();
  if (tid == 0) {
    unsigned cum = s_excl;
    int bin = s_chunk * 16;
    while (cum + hist[bin] < KNN) {
      cum += hist[bin];
      ++bin;
    }
    s_bub = (unsigned)(bin + 1) << 19;  // exclusive upper bound on bits
  }
  __syncthreads();

  // ---------------- Phase C: exact cover cube, filter bits < bound
  const unsigned bub = s_bub;
  const float dub = __uint_as_float(bub);
  if (tid == 0) s_mc = 0;
  __syncthreads();
  {
    int xlo2 = min(max((int)floorf((qx - dub + GB) * GINVH), 0), G - 1);
    int xhi2 = min(max((int)floorf((qx + dub + GB) * GINVH), 0), G - 1);
    int ylo2 = min(max((int)floorf((qy - dub + GB) * GINVH), 0), G - 1);
    int yhi2 = min(max((int)floorf((qy + dub + GB) * GINVH), 0), G - 1);
    int zlo2 = min(max((int)floorf((qz - dub + GB) * GINVH), 0), G - 1);
    int zhi2 = min(max((int)floorf((qz + dub + GB) * GINVH), 0), G - 1);
    int nx = xhi2 - xlo2 + 1, ny = yhi2 - ylo2 + 1, nz = zhi2 - zlo2 + 1;
    int ncell = nx * ny * nz;
    for (int ci = tid; ci < ncell; ci += 256) {
      int cz = ci % nz;
      int r = ci / nz;
      int cy = r % ny;
      int cx = r / ny;
      int cell = ((xlo2 + cx) << 12) | ((ylo2 + cy) << 6) | (zlo2 + cz);
      unsigned end = cursor[cell];
      unsigned beg = end - cnt[cell];
      for (unsigned p = beg; p < end; ++p) {
        float4 f = sorted[p];
        unsigned bits = linf_bits(f.x, f.y, f.z, qx, qy, qz);
        if (bits < bub) {
          int e = atomicAdd(&s_mc, 1);
          if (e < CAND_CAP) {
            cbits[e] = bits;
            cidx[e] = __float_as_int(f.w);
          }
        }
      }
    }
  }
  __syncthreads();
  int mc = s_mc < CAND_CAP ? s_mc : CAND_CAP;

  // ---------------- exact rank-select (ties by original index, stable)
  for (int c = tid; c < mc; c += 256) {
    unsigned bc = cbits[c];
    int ic = cidx[c];
    int rank = 0;
    for (int j = 0; j < mc; ++j) {
      unsigned bj = cbits[j];
      rank += (bj < bc || (bj == bc && cidx[j] < ic)) ? 1 : 0;
    }
    if (rank < KNN) nbr[b * KNN + rank] = ic;
  }
}

// ---------------------------------------- KPConv + conv1 FUSED (f16 MFMA)
// Phase 1 (kpconv, hi/lo split): h[100x128] = relu(A[100x64] x kpwT^T),
// kept in LDS as f16 (bit-identical to the old global h round-trip).
// Phase 2 (conv1): loop 8 chunks of 128 output channels; stage wh chunk in
// LDS; MFMA Hs x Ws; fused max/min/sum/sq epilogue. LDS phase-overlaid:
// As/Bs (69KB, dead after phase 1) are overlaid by Hs+Ws (65KB).
__global__ __launch_bounds__(256) void kpconv_conv1_kernel(
    const float* __restrict__ pts, const float* __restrict__ sel,
    const int* __restrict__ nbr, const float* __restrict__ kp_points,
    const __half* __restrict__ kpwT_hi, const __half* __restrict__ kpwT_lo,
    const float* __restrict__ kp_sigma, const __half* __restrict__ wh,
    const float* __restrict__ bias, float* __restrict__ featmax,
    float* __restrict__ featmin, float* __restrict__ bnsum,
    float* __restrict__ bnsq) {
  const int b = blockIdx.x;
  const int tid = threadIdx.x;
  const int wave = tid >> 6, lane = tid & 63;
  const int lr = lane & 15, quad = lane >> 4;

  __shared__ __align__(16) char smem[71168];
  // phase-1 carve
  __half* As_hi = (__half*)smem;              // 112*72 halfs
  __half* As_lo = As_hi + 112 * 72;
  __half* Bs_hi = As_lo + 112 * 72;           // 128*72 halfs
  __half* Bs_lo = Bs_hi + 128 * 72;
  float* rel = (float*)(Bs_lo + 128 * 72);    // 100*4 floats
  float* kpp = rel + 100 * 4;                 // 48 floats
  // phase-2 overlay (same smem)
  __half* Hs = (__half*)smem;                 // 112*136 halfs = 30464 B
  __half* Ws = Hs + 112 * 136;                // 128*136 halfs = 34816 B

  // ---- phase 1 staging
  for (int i = tid; i < 128 * 8; i += 256) {
    int row = i >> 3, seg = i & 7;
    *(float4*)&Bs_hi[row * 72 + seg * 8] =
        *(const float4*)&kpwT_hi[row * 64 + seg * 8];
    *(float4*)&Bs_lo[row * 72 + seg * 8] =
        *(const float4*)&kpwT_lo[row * 64 + seg * 8];
  }
  {
    float4 z = make_float4(0.f, 0.f, 0.f, 0.f);
    for (int i = tid; i < 112 * 8; i += 256) {
      int row = i >> 3, seg = i & 7;
      *(float4*)&As_hi[row * 72 + seg * 8] = z;
      *(float4*)&As_lo[row * 72 + seg * 8] = z;
    }
  }
  if (tid < 45) kpp[tid] = kp_points[tid];
  if (tid < 100) {
    int idx = nbr[b * KNN + tid];
    rel[tid * 4 + 0] = pts[3 * idx + 0] - sel[b * 3 + 0];
    rel[tid * 4 + 1] = pts[3 * idx + 1] - sel[b * 3 + 1];
    rel[tid * 4 + 2] = pts[3 * idx + 2] - sel[b * 3 + 2];
  }
  __syncthreads();

  const float sg = kp_sigma[0];
  const float inv2s2 = -0.5f / (sg * sg);
  for (int i = tid; i < 100 * KPN; i += 256) {
    int k = i / KPN, p = i - k * KPN;
    float rx = rel[k * 4 + 0] - kpp[p * 3 + 0];
    float ry = rel[k * 4 + 1] - kpp[p * 3 + 1];
    float rz = rel[k * 4 + 2] - kpp[p * 3 + 2];
    float w = expf(inv2s2 * (rx * rx + ry * ry + rz * rz));
#pragma unroll
    for (int c = 0; c < 3; ++c) {
      float a = rel[k * 4 + c] * w;
      __half hi = __float2half_rn(a);
      As_hi[k * 72 + p * 3 + c] = hi;
      As_lo[k * 72 + p * 3 + c] = __float2half_rn(a - __half2float(hi));
    }
  }
  __syncthreads();

  // ---- phase 1 MFMA: acc = Ahi*Bhi + Ahi*Blo + Alo*Bhi
  f32x4 acc[2][7];
#pragma unroll
  for (int t = 0; t < 2; ++t)
#pragma unroll
    for (int m = 0; m < 7; ++m) acc[t][m] = (f32x4)(0.f);

#pragma unroll
  for (int s = 0; s < 2; ++s) {
    half8 bhi[2], blo[2];
#pragma unroll
    for (int t = 0; t < 2; ++t) {
      int boff = ((wave * 2 + t) * 16 + lr) * 72 + s * 32 + quad * 8;
      bhi[t] = *(const half8*)&Bs_hi[boff];
      blo[t] = *(const half8*)&Bs_lo[boff];
    }
#pragma unroll
    for (int m = 0; m < 7; ++m) {
      int aoff = (m * 16 + lr) * 72 + s * 32 + quad * 8;
      half8 ahi = *(const half8*)&As_hi[aoff];
      half8 alo = *(const half8*)&As_lo[aoff];
#pragma unroll
      for (int t = 0; t < 2; ++t) {
        acc[t][m] = __builtin_amdgcn_mfma_f32_16x16x32_f16(ahi, bhi[t],
                                                           acc[t][m], 0, 0, 0);
        acc[t][m] = __builtin_amdgcn_mfma_f32_16x16x32_f16(ahi, blo[t],
                                                           acc[t][m], 0, 0, 0);
        acc[t][m] = __builtin_amdgcn_mfma_f32_16x16x32_f16(alo, bhi[t],
                                                           acc[t][m], 0, 0, 0);
      }
    }
  }
  __syncthreads();  // As/Bs dead; safe to overlay Hs/Ws

  // ---- write h tile to LDS (rows>=100 are zero since As rows were zeroed)
#pragma unroll
  for (int t = 0; t < 2; ++t) {
    int col = (wave * 2 + t) * 16 + lr;
#pragma unroll
    for (int m = 0; m < 7; ++m)
#pragma unroll
      for (int r = 0; r < 4; ++r) {
        int row = m * 16 + quad * 4 + r;
        Hs[row * 136 + col] = __float2half_rn(fmaxf(acc[t][m][r], 0.f));
      }
  }

  // ---- phase 2: 8 chunks of 128 output channels
  for (int c = 0; c < 8; ++c) {
    __syncthreads();  // prior chunk's MFMA done reading Ws (and c=0: Hs/Ws writes ordered)
    for (int i = tid; i < 128 * 16; i += 256) {
      int row = i >> 4, seg = i & 15;
      *(float4*)&Ws[row * 136 + seg * 8] =
          *(const float4*)&wh[(c * 128 + row) * 128 + seg * 8];
    }
    __syncthreads();

    f32x4 acc2[2][7];
#pragma unroll
    for (int t = 0; t < 2; ++t)
#pragma unroll
      for (int m = 0; m < 7; ++m) acc2[t][m] = (f32x4)(0.f);

#pragma unroll
    for (int s = 0; s < 4; ++s) {
      half8 bfrag[2];
#pragma unroll
      for (int t = 0; t < 2; ++t)
        bfrag[t] = *(const half8*)&Ws[((wave * 2 + t) * 16 + lr) * 136 +
                                      s * 32 + quad * 8];
#pragma unroll
      for (int m = 0; m < 7; ++m) {
        half8 afrag =
            *(const half8*)&Hs[(m * 16 + lr) * 136 + s * 32 + quad * 8];
        acc2[0][m] = __builtin_amdgcn_mfma_f32_16x16x32_f16(afrag, bfrag[0],
                                                            acc2[0][m], 0, 0, 0);
        acc2[1][m] = __builtin_amdgcn_mfma_f32_16x16x32_f16(afrag, bfrag[1],
                                                            acc2[1][m], 0, 0, 0);
      }
    }

#pragma unroll
    for (int t = 0; t < 2; ++t) {
      int col = c * 128 + (wave * 2 + t) * 16 + lr;
      float bv = bias[col];
      float pmax = -1e30f, pmin = 1e30f, psum = 0.f, psq = 0.f;
#pragma unroll
      for (int m = 0; m < 7; ++m)
#pragma unroll
        for (int r = 0; r < 4; ++r) {
          int row = m * 16 + quad * 4 + r;
          if (row < 100) {
            float y = fmaxf(acc2[t][m][r] + bv, 0.f);
            pmax = fmaxf(pmax, y);
            pmin = fminf(pmin, y);
            psum += y;
            psq += y * y;
          }
        }
      pmax = fmaxf(pmax, __shfl_xor(pmax, 16));
      pmax = fmaxf(pmax, __shfl_xor(pmax, 32));
      pmin = fminf(pmin, __shfl_xor(pmin, 16));
      pmin = fminf(pmin, __shfl_xor(pmin, 32));
      psum += __shfl_xor(psum, 16);
      psum += __shfl_xor(psum, 32);
      psq += __shfl_xor(psq, 16);
      psq += __shfl_xor(psq, 32);
      if (quad == 0) {
        featmax[b * C2 + col] = pmax;
        featmin[b * C2 + col] = pmin;
        atomicAdd(&bnsum[col], psum);
        atomicAdd(&bnsq[col], psq);
      }
    }
  }
}

// ------------------------------------------------------- BN1 + max finalize
__global__ __launch_bounds__(256) void bn1max_kernel(
    const float* __restrict__ featmax, const float* __restrict__ featmin,
    const float* __restrict__ bnsum, const float* __restrict__ bnsq,
    const float* __restrict__ g, const float* __restrict__ bb,
    float* __restrict__ feat1) {
  int idx = blockIdx.x * 256 + threadIdx.x;
  if (idx >= NB * C2) return;
  int o = idx & (C2 - 1);
  const float invn = 1.f / (float)(NB * KNN);
  float m = bnsum[o] * invn;
  float v = bnsq[o] * invn - m * m;
  float a = g[o] / sqrtf(v + 1e-5f);
  float x = (a >= 0.f) ? featmax[idx] : featmin[idx];  // max of monotone map
  feat1[idx] = (x - m) * a + bb[o];
}

// ---------------------------------------------------------------- fc + stats
template <int KDIM>
__global__ __launch_bounds__(256) void fc_relu_stats_kernel(
    const float* __restrict__ x,  // [500][KDIM]
    const float* __restrict__ w,  // [N][KDIM]
    const float* __restrict__ bias, float* __restrict__ yraw,
    float* __restrict__ s, float* __restrict__ sq, int ncols) {
  const int r0 = blockIdx.x * 4;
  const int n0 = blockIdx.y * 64;
  const int tid = threadIdx.x;
  const int col = tid >> 2;  // 0..63
  const int row = tid & 3;
  __shared__ float xs[4][1028];
  __shared__ float ws[64][132];
  for (int f = tid; f < KDIM; f += 256) {  // KDIM float4's total
    int rr = f / (KDIM / 4), kq = (f % (KDIM / 4)) * 4;
    *(float4*)&xs[rr][kq] = *(const float4*)&x[(r0 + rr) * KDIM + kq];
  }
  float acc = 0.f;
  for (int kc = 0; kc < KDIM; kc += 128) {
    __syncthreads();
#pragma unroll
    for (int i = 0; i < 8; ++i) {
      int f = tid + i * 256;  // 0..2047
      int cr = f >> 5, kq = (f & 31) * 4;
      *(float4*)&ws[cr][kq] = *(const float4*)&w[(n0 + cr) * KDIM + kc + kq];
    }
    __syncthreads();
    for (int kk = 0; kk < 128; kk += 4) {
      float4 xv = *(float4*)&xs[row][kc + kk];
      float4 wv = *(float4*)&ws[col][kk];
      acc += xv.x * wv.x + xv.y * wv.y + xv.z * wv.z + xv.w * wv.w;
    }
  }
  float y = fmaxf(acc + bias[n0 + col], 0.f);
  yraw[(r0 + row) * ncols + n0 + col] = y;
  float ys = y, y2 = y * y;
  ys += __shfl_xor(ys, 1); y2 += __shfl_xor(y2, 1);
  ys += __shfl_xor(ys, 2); y2 += __shfl_xor(y2, 2);
  if (row == 0) {
    atomicAdd(&s[n0 + col], ys);
    atomicAdd(&sq[n0 + col], y2);
  }
}

// ---------------------------------------------------------------- BN finalize
__global__ __launch_bounds__(256) void bn_finalize_kernel(
    const float* __restrict__ yraw, const float* __restrict__ s,
    const float* __restrict__ sq, const float* __restrict__ g,
    const float* __restrict__ bb, float* __restrict__ out, int ncols) {
  int idx = blockIdx.x * 256 + threadIdx.x;
  if (idx >= NB * ncols) return;
  int o = idx & (ncols - 1);  // ncols is a power of two
  float m = s[o] * (1.f / (float)NB);
  float v = sq[o] * (1.f / (float)NB) - m * m;
  float a = g[o] / sqrtf(v + 1e-5f);
  out[idx] = (yraw[idx] - m) * a + bb[o];
}

// ---------------------------------------------------------------- fc3
__global__ __launch_bounds__(256) void fc3_kernel(
    const float* __restrict__ feat, const float* __restrict__ w,
    const float* __restrict__ bias, float* __restrict__ out) {
  int idx = blockIdx.x * 256 + threadIdx.x;
  if (idx >= NB * 3) return;
  int b = idx / 3, o = idx % 3;
  float acc = 0.f;
  for (int k = 0; k < C4; ++k) acc += feat[b * C4 + k] * w[o * C4 + k];
  out[idx] = acc + bias[o];
}

// ---------------------------------------------------------------- launch
extern "C" void kernel_launch(void* const* d_in, const int* in_sizes, int n_in,
                              void* d_out, int out_size, void* d_ws,
                              size_t ws_size, hipStream_t stream) {
  const float* pts = (const float*)d_in[0];
  const float* normal = (const float*)d_in[1];
  const float* kp_points = (const float*)d_in[2];
  const float* kp_weights = (const float*)d_in[3];
  const float* kp_sigma = (const float*)d_in[4];
  const float* conv1_w = (const float*)d_in[5];
  const float* conv1_b = (const float*)d_in[6];
  const float* bn1_g = (const float*)d_in[7];
  const float* bn1_b = (const float*)d_in[8];
  const float* fc1_w = (const float*)d_in[9];
  const float* fc1_b = (const float*)d_in[10];
  const float* bn4_g = (const float*)d_in[11];
  const float* bn4_b = (const float*)d_in[12];
  const float* fc2_w = (const float*)d_in[13];
  const float* fc2_b = (const float*)d_in[14];
  const float* bn5_g = (const float*)d_in[15];
  const float* bn5_b = (const float*)d_in[16];
  const float* fc3_w = (const float*)d_in[17];
  const float* fc3_b = (const float*)d_in[18];
  const int* index = (const int*)d_in[19];
  float* out = (float*)d_out;

  char* p = (char*)d_ws;
  auto carve = [&](size_t bytes) {
    void* r = (void*)p;
    p += (bytes + 255) & ~(size_t)255;
    return r;
  };
  float* sel = (float*)carve(NB * 3 * 4);
  int* nbr = (int*)carve(NB * KNN * 4);
  __half* wh = (__half*)carve((size_t)C2 * C1 * 2);
  __half* kpwT_hi = (__half*)carve((size_t)128 * 64 * 2);
  __half* kpwT_lo = (__half*)carve((size_t)128 * 64 * 2);
  float* featmax = (float*)carve(NB * C2 * 4);
  float* featmin = (float*)carve(NB * C2 * 4);
  float* feat1 = (float*)carve(NB * C2 * 4);
  float* f2raw = (float*)carve(NB * C3 * 4);
  float* feat2 = (float*)carve(NB * C3 * 4);
  float* f3raw = (float*)carve(NB * C4 * 4);
  float* feat3 = (float*)carve(NB * C4 * 4);
  float* stats = (float*)carve((2 * C2 + 2 * C3 + 2 * C4) * 4);
  float* bnsum = stats;
  float* bnsq = stats + C2;
  float* s4 = stats + 2 * C2;
  float* sq4 = s4 + C3;
  float* s5 = sq4 + C3;
  float* sq5 = s5 + C4;
  // grid structures (dedicated carve; h buffer no longer exists)
  unsigned* cellcnt = (unsigned*)carve((size_t)NCELLS * 4);
  unsigned* cellcur = (unsigned*)carve((size_t)NCELLS * 4);
  unsigned* chunktot = (unsigned*)carve(256 * 4);
  unsigned* chunkoff = (unsigned*)carve(256 * 4);
  float4* sortedpts = (float4*)carve((size_t)NPTS * 16);

  hipMemsetAsync(stats, 0, (2 * C2 + 2 * C3 + 2 * C4) * 4, stream);
  hipMemsetAsync(cellcnt, 0, (size_t)NCELLS * 4, stream);

  prep_kernel<<<(C2 * C1 + 255) / 256, 256, 0, stream>>>(
      pts, normal, index, conv1_w, kp_weights, sel, out + NB * 3, wh, kpwT_hi,
      kpwT_lo);
  grid_hist_kernel<<<(NPTS + 255) / 256, 256, 0, stream>>>(pts, cellcnt);
  grid_scan1_kernel<<<256, 256, 0, stream>>>(cellcnt, cellcur, chunktot);
  grid_scan2_kernel<<<1, 256, 0, stream>>>(chunktot, chunkoff);
  grid_scan3_kernel<<<256, 256, 0, stream>>>(cellcur, chunkoff);
  grid_scatter_kernel<<<(NPTS + 255) / 256, 256, 0, stream>>>(pts, cellcur,
                                                              sortedpts);
  knn_kernel<<<NB, 256, 0, stream>>>(sortedpts, cellcnt, cellcur, sel, nbr);
  kpconv_conv1_kernel<<<NB, 256, 0, stream>>>(
      pts, sel, nbr, kp_points, kpwT_hi, kpwT_lo, kp_sigma, wh, conv1_b,
      featmax, featmin, bnsum, bnsq);
  bn1max_kernel<<<(NB * C2 + 255) / 256, 256, 0, stream>>>(
      featmax, featmin, bnsum, bnsq, bn1_g, bn1_b, feat1);
  fc_relu_stats_kernel<C2><<<dim3(125, C3 / 64), 256, 0, stream>>>(
      feat1, fc1_w, fc1_b, f2raw, s4, sq4, C3);
  bn_finalize_kernel<<<(NB * C3 + 255) / 256, 256, 0, stream>>>(
      f2raw, s4, sq4, bn4_g, bn4_b, feat2, C3);
  fc_relu_stats_kernel<C3><<<dim3(125, C4 / 64), 256, 0, stream>>>(
      feat2, fc2_w, fc2_b, f3raw, s5, sq5, C4);
  bn_finalize_kernel<<<(NB * C4 + 255) / 256, 256, 0, stream>>>(
      f3raw, s5, sq5, bn5_g, bn5_b, feat3, C4);
  fc3_kernel<<<(NB * 3 + 255) / 256, 256, 0, stream>>>(feat3, fc3_w, fc3_b,
                                                       out);
}